// Round 3
// baseline (938.153 us; speedup 1.0000x reference)
//
#include <hip/hip_runtime.h>

// BlockHadamardDPD: out[r, d] = (FWHT64(x[r]) / 8 * sign1)[perm[d]] * sign2[d]
// B*S = 32768 rows, DIM = 4096 fp32. Memory-bound: 1.07 GiB compulsory traffic.
//
// One block per row, 256 threads, 16 elements/thread.
// FWHT-64 in registers (dist 1/2/4/8 in-thread, dist 16/32 via shfl_xor 1/2),
// LDS used only to resolve the arbitrary permutation gather.

constexpr int DIM = 4096;
constexpr int TPB = 256;          // threads per block
constexpr int EPT = DIM / TPB;    // 16 elements per thread

__global__ __launch_bounds__(TPB)
void bh_dpd_kernel(const float* __restrict__ x,
                   const float* __restrict__ sign1,
                   const float* __restrict__ sign2,
                   const int*   __restrict__ perm,
                   float* __restrict__ out)
{
    __shared__ float h[DIM];

    const int t = threadIdx.x;
    const long long row = blockIdx.x;
    const float* xr   = x   + row * (long long)DIM;
    float*       outr = out + row * (long long)DIM;

    const int base = t * EPT;     // 16 consecutive elements per thread

    // ---- coalesced load (4 x float4 per thread) ----
    float v[EPT];
    {
        const float4* xv = reinterpret_cast<const float4*>(xr + base);
        #pragma unroll
        for (int j = 0; j < EPT / 4; ++j) {
            float4 a = xv[j];
            v[j*4+0] = a.x; v[j*4+1] = a.y; v[j*4+2] = a.z; v[j*4+3] = a.w;
        }
    }

    // ---- FWHT-64 within each 64-element block ----
    // thread t holds quarter (t&3) of its 64-block; elements are contiguous.
    // In-register stages: butterfly distances 1, 2, 4, 8.
    #pragma unroll
    for (int s = 1; s <= 8; s <<= 1) {
        #pragma unroll
        for (int i = 0; i < EPT; ++i) {
            if ((i & s) == 0) {
                float a = v[i], b = v[i + s];
                v[i]     = a + b;
                v[i + s] = a - b;
            }
        }
    }
    // Cross-lane stages: distance 16 -> lane xor 1, distance 32 -> lane xor 2.
    // Threads 4b..4b+3 own block b and sit in the same 64-lane wave.
    #pragma unroll
    for (int i = 0; i < EPT; ++i) {
        float p = __shfl_xor(v[i], 1, 64);
        v[i] = (t & 1) ? (p - v[i]) : (v[i] + p);
    }
    #pragma unroll
    for (int i = 0; i < EPT; ++i) {
        float p = __shfl_xor(v[i], 2, 64);
        v[i] = (t & 2) ? (p - v[i]) : (v[i] + p);
    }

    // ---- scale by 1/sqrt(64)=0.125, apply sign1, stage into LDS ----
    {
        const float4* s1v = reinterpret_cast<const float4*>(sign1 + base);
        float4* hv = reinterpret_cast<float4*>(h + base);
        #pragma unroll
        for (int j = 0; j < EPT / 4; ++j) {
            float4 s = s1v[j];
            float4 o;
            o.x = v[j*4+0] * 0.125f * s.x;
            o.y = v[j*4+1] * 0.125f * s.y;
            o.z = v[j*4+2] * 0.125f * s.z;
            o.w = v[j*4+3] * 0.125f * s.w;
            hv[j] = o;
        }
    }
    __syncthreads();

    // ---- permutation gather + sign2, coalesced stores ----
    {
        const int4*   pv  = reinterpret_cast<const int4*>(perm  + base);
        const float4* s2v = reinterpret_cast<const float4*>(sign2 + base);
        float4* ov = reinterpret_cast<float4*>(outr + base);
        #pragma unroll
        for (int j = 0; j < EPT / 4; ++j) {
            int4   p = pv[j];
            float4 s = s2v[j];
            float4 o;
            o.x = h[p.x] * s.x;
            o.y = h[p.y] * s.y;
            o.z = h[p.z] * s.z;
            o.w = h[p.w] * s.w;
            ov[j] = o;
        }
    }
}

extern "C" void kernel_launch(void* const* d_in, const int* in_sizes, int n_in,
                              void* d_out, int out_size, void* d_ws, size_t ws_size,
                              hipStream_t stream) {
    const float* x     = (const float*)d_in[0];
    const float* sign1 = (const float*)d_in[1];
    const float* sign2 = (const float*)d_in[2];
    const int*   perm  = (const int*)d_in[3];
    float* out = (float*)d_out;

    const int rows = out_size / DIM;   // B*S = 32768
    bh_dpd_kernel<<<dim3(rows), dim3(TPB), 0, stream>>>(x, sign1, sign2, perm, out);
}

// Round 7
// 843.558 us; speedup vs baseline: 1.1121x; 1.1121x over previous
//
#include <hip/hip_runtime.h>

// BlockHadamardDPD: out[r, d] = (FWHT64(x[r]) / 8 * sign1)[perm[d]] * sign2[d]
// 32768 rows x 4096 fp32. HBM-bound: ~1.07 GiB compulsory traffic.
//
// Coalescing-first layout: lane t owns float4 at (1024*j + 4*t), j=0..3, so
// every wave-level VMEM instruction is 1024 B contiguous (vs 64B-strided in
// the round-3 version, which touched 64 cache lines per instruction).
// FWHT-64: element position within its 64-block is 4*(lane&15)+k, so
//   dist 1,2  -> in-register on the float4
//   dist 4,8,16,32 -> __shfl_xor masks 1,2,4,8 (within 16-lane rows, DPP-able)
// LDS used only to resolve the arbitrary permutation gather.
//
// NOTE: __builtin_nontemporal_* requires a native clang vector type, not
// HIP_vector_type<float,4> — hence f32x4/i32x4 ext_vector_type below.

constexpr int DIM = 4096;
constexpr int TPB = 256;
constexpr int NG  = DIM / (TPB * 4);   // 4 float4-groups per thread

typedef float f32x4 __attribute__((ext_vector_type(4)));
typedef int   i32x4 __attribute__((ext_vector_type(4)));

__global__ __launch_bounds__(TPB)
void bh_dpd_kernel(const float* __restrict__ x,
                   const float* __restrict__ sign1,
                   const float* __restrict__ sign2,
                   const int*   __restrict__ perm,
                   float* __restrict__ out)
{
    __shared__ float h[DIM];

    const int t = threadIdx.x;
    const int l = t & 63;                   // lane within wave
    const long long row = blockIdx.x;
    const float* xr   = x   + row * (long long)DIM;
    float*       outr = out + row * (long long)DIM;

    // ---- coalesced streaming load: lane-contiguous float4 ----
    f32x4 g[NG];
    #pragma unroll
    for (int j = 0; j < NG; ++j) {
        const f32x4* src = reinterpret_cast<const f32x4*>(xr + j * 1024) + t;
        g[j] = __builtin_nontemporal_load(src);
    }

    // ---- FWHT-64, stages dist 1 and 2 in-register ----
    #pragma unroll
    for (int j = 0; j < NG; ++j) {
        float a0 = g[j].x, a1 = g[j].y, a2 = g[j].z, a3 = g[j].w;
        float b0 = a0 + a1, b1 = a0 - a1;       // dist 1
        float b2 = a2 + a3, b3 = a2 - a3;
        g[j].x = b0 + b2; g[j].y = b1 + b3;     // dist 2
        g[j].z = b0 - b2; g[j].w = b1 - b3;
    }

    // ---- stages dist 4,8,16,32 -> lane xor 1,2,4,8 ----
    #pragma unroll
    for (int m = 1; m <= 8; m <<= 1) {
        const bool hi = (l & m) != 0;
        #pragma unroll
        for (int j = 0; j < NG; ++j) {
            float px = __shfl_xor(g[j].x, m, 64);
            float py = __shfl_xor(g[j].y, m, 64);
            float pz = __shfl_xor(g[j].z, m, 64);
            float pw = __shfl_xor(g[j].w, m, 64);
            g[j].x = hi ? (px - g[j].x) : (g[j].x + px);
            g[j].y = hi ? (py - g[j].y) : (g[j].y + py);
            g[j].z = hi ? (pz - g[j].z) : (g[j].z + pz);
            g[j].w = hi ? (pw - g[j].w) : (g[j].w + pw);
        }
    }

    // ---- scale 1/8, apply sign1, stage into LDS (contiguous b128) ----
    #pragma unroll
    for (int j = 0; j < NG; ++j) {
        f32x4 s = reinterpret_cast<const f32x4*>(sign1 + j * 1024)[t];
        f32x4 o;
        o.x = g[j].x * 0.125f * s.x;
        o.y = g[j].y * 0.125f * s.y;
        o.z = g[j].z * 0.125f * s.z;
        o.w = g[j].w * 0.125f * s.w;
        reinterpret_cast<f32x4*>(h + j * 1024)[t] = o;
    }
    __syncthreads();

    // ---- permutation gather + sign2, coalesced nontemporal stores ----
    #pragma unroll
    for (int j = 0; j < NG; ++j) {
        i32x4 p = reinterpret_cast<const i32x4*>(perm + j * 1024)[t];
        f32x4 s = reinterpret_cast<const f32x4*>(sign2 + j * 1024)[t];
        f32x4 o;
        o.x = h[p.x] * s.x;
        o.y = h[p.y] * s.y;
        o.z = h[p.z] * s.z;
        o.w = h[p.w] * s.w;
        __builtin_nontemporal_store(o, reinterpret_cast<f32x4*>(outr + j * 1024) + t);
    }
}

extern "C" void kernel_launch(void* const* d_in, const int* in_sizes, int n_in,
                              void* d_out, int out_size, void* d_ws, size_t ws_size,
                              hipStream_t stream) {
    const float* x     = (const float*)d_in[0];
    const float* sign1 = (const float*)d_in[1];
    const float* sign2 = (const float*)d_in[2];
    const int*   perm  = (const int*)d_in[3];
    float* out = (float*)d_out;

    const int rows = out_size / DIM;   // B*S = 32768
    bh_dpd_kernel<<<dim3(rows), dim3(TPB), 0, stream>>>(x, sign1, sign2, perm, out);
}